// Round 2
// baseline (1734.027 us; speedup 1.0000x reference)
//
#include <hip/hip_runtime.h>
#include <hip/hip_bf16.h>

#define N_NODES 50000
#define N_EDGES 800000
#define F 128

// ---------------- Edge pass 1: wsum + deg via atomics ----------------
__global__ __launch_bounds__(256) void edge_pass1(const float* __restrict__ efeat,
                                                  const int* __restrict__ dst,
                                                  float* __restrict__ wsum,
                                                  float* __restrict__ deg) {
    int e = blockIdx.x * 256 + threadIdx.x;
    if (e < N_EDGES) {
        float w = efeat[e];
        int d = dst[e];
        atomicAdd(&wsum[d], w);
        atomicAdd(&deg[d], 1.0f);
    }
}

// ---------------- Edge pass 2: m = exp(-w/wsum[dst]); aggF[dst] += m*feat[src]; msum[dst] += m
// 32 lanes per edge, each lane handles a float4 (32*4 = 128 feats).
__global__ __launch_bounds__(256) void edge_pass2(const float* __restrict__ efeat,
                                                  const int* __restrict__ src,
                                                  const int* __restrict__ dst,
                                                  const float* __restrict__ feat,
                                                  const float* __restrict__ wsum,
                                                  float* __restrict__ msum,
                                                  float* __restrict__ aggF) {
    int tid  = threadIdx.x;
    int sub  = tid >> 5;          // 8 edges per block
    int lane = tid & 31;
    int e = blockIdx.x * 8 + sub;
    if (e >= N_EDGES) return;
    int d = dst[e];
    int s = src[e];
    float w = efeat[e];
    float m = __expf(-w / wsum[d]);   // wsum[d] > 0 whenever edge e targets d
    if (lane == 0) atomicAdd(&msum[d], m);
    const float4* fs = (const float4*)(feat + (size_t)s * F);
    float4 v = fs[lane];
    float* ag = aggF + (size_t)d * F + lane * 4;
    atomicAdd(ag + 0, m * v.x);
    atomicAdd(ag + 1, m * v.y);
    atomicAdd(ag + 2, m * v.z);
    atomicAdd(ag + 3, m * v.w);
}

// ---------------- Fused dual GEMM + epilogue ----------------
// out[n][o] = dot(feat[n], Ws[o]) + bs[o] + (dot(aggF[n], Wp[o]) + msum[n]*bp[o]) / max(deg[n],1)
// Block: 256 threads, 16 nodes. Thread t: cols {cg, cg+64} (cg=t&63), nodes {rg+4r} (rg=t>>6).
__global__ __launch_bounds__(256) void fused_gemm(const float* __restrict__ feat,
                                                  const float* __restrict__ aggF,
                                                  const float* __restrict__ Wp,
                                                  const float* __restrict__ bp,
                                                  const float* __restrict__ Ws,
                                                  const float* __restrict__ bs,
                                                  const float* __restrict__ msum,
                                                  const float* __restrict__ deg,
                                                  float* __restrict__ out) {
    __shared__ float sF[16][F];
    __shared__ float sA[16][F];
    int t  = threadIdx.x;
    int n0 = blockIdx.x * 16;

    // cooperative tile load: 16 rows x 32 float4/row = 512 float4 per array
    for (int i = t; i < 512; i += 256) {
        int node = i >> 5;        // row: 32 float4 per row of 128 floats
        int c4   = i & 31;
        int gn   = n0 + node;
        float4 f4 = make_float4(0.f, 0.f, 0.f, 0.f);
        float4 a4 = make_float4(0.f, 0.f, 0.f, 0.f);
        if (gn < N_NODES) {
            f4 = ((const float4*)(feat + (size_t)gn * F))[c4];
            a4 = ((const float4*)(aggF + (size_t)gn * F))[c4];
        }
        ((float4*)&sF[node][0])[c4] = f4;
        ((float4*)&sA[node][0])[c4] = a4;
    }
    __syncthreads();

    int cg = t & 63;
    int rg = t >> 6;
    float accS[4][2] = {{0.f,0.f},{0.f,0.f},{0.f,0.f},{0.f,0.f}};
    float accP[4][2] = {{0.f,0.f},{0.f,0.f},{0.f,0.f},{0.f,0.f}};

    const float4* ws0 = (const float4*)(Ws + (size_t)cg * F);
    const float4* ws1 = (const float4*)(Ws + (size_t)(cg + 64) * F);
    const float4* wp0 = (const float4*)(Wp + (size_t)cg * F);
    const float4* wp1 = (const float4*)(Wp + (size_t)(cg + 64) * F);

    #pragma unroll 4
    for (int k4 = 0; k4 < F / 4; ++k4) {
        float4 w0 = ws0[k4], w1 = ws1[k4];
        float4 p0 = wp0[k4], p1 = wp1[k4];
        #pragma unroll
        for (int r = 0; r < 4; ++r) {
            int node = rg + r * 4;
            float4 f = ((const float4*)&sF[node][0])[k4];
            float4 a = ((const float4*)&sA[node][0])[k4];
            accS[r][0] += f.x*w0.x + f.y*w0.y + f.z*w0.z + f.w*w0.w;
            accS[r][1] += f.x*w1.x + f.y*w1.y + f.z*w1.z + f.w*w1.w;
            accP[r][0] += a.x*p0.x + a.y*p0.y + a.z*p0.z + a.w*p0.w;
            accP[r][1] += a.x*p1.x + a.y*p1.y + a.z*p1.z + a.w*p1.w;
        }
    }

    float bs0 = bs[cg], bs1 = bs[cg + 64];
    float bp0 = bp[cg], bp1 = bp[cg + 64];
    #pragma unroll
    for (int r = 0; r < 4; ++r) {
        int gn = n0 + rg + r * 4;
        if (gn >= N_NODES) continue;
        float dv = fmaxf(deg[gn], 1.0f);
        float ms = msum[gn];
        float inv = 1.0f / dv;
        out[(size_t)gn * F + cg]      = accS[r][0] + bs0 + (accP[r][0] + ms * bp0) * inv;
        out[(size_t)gn * F + cg + 64] = accS[r][1] + bs1 + (accP[r][1] + ms * bp1) * inv;
    }
}

extern "C" void kernel_launch(void* const* d_in, const int* in_sizes, int n_in,
                              void* d_out, int out_size, void* d_ws, size_t ws_size,
                              hipStream_t stream) {
    const float* feat  = (const float*)d_in[0];
    const float* efeat = (const float*)d_in[1];
    const int*   src   = (const int*)d_in[2];
    const int*   dst   = (const int*)d_in[3];
    const float* Wp    = (const float*)d_in[4];
    const float* bp    = (const float*)d_in[5];
    const float* Ws    = (const float*)d_in[6];
    const float* bs    = (const float*)d_in[7];
    float* out = (float*)d_out;

    float* ws_f  = (float*)d_ws;
    float* wsum  = ws_f;
    float* deg   = ws_f + N_NODES;
    float* msum  = ws_f + 2 * N_NODES;
    float* aggF  = ws_f + 3 * N_NODES;   // byte offset 600000, 16B-aligned

    size_t zero_bytes = (size_t)(3 * N_NODES + (size_t)N_NODES * F) * sizeof(float);
    hipMemsetAsync(d_ws, 0, zero_bytes, stream);

    edge_pass1<<<(N_EDGES + 255) / 256, 256, 0, stream>>>(efeat, dst, wsum, deg);
    edge_pass2<<<(N_EDGES + 7) / 8, 256, 0, stream>>>(efeat, src, dst, feat, wsum, msum, aggF);
    fused_gemm<<<(N_NODES + 15) / 16, 256, 0, stream>>>(feat, aggF, Wp, bp, Ws, bs, msum, deg, out);
}

// Round 3
// 580.369 us; speedup vs baseline: 2.9878x; 2.9878x over previous
//
#include <hip/hip_runtime.h>
#include <hip/hip_bf16.h>

#define N_NODES 50000
#define N_EDGES 800000
#define F 128
#define SCAN_T 1024

// ---------------- k_count: integer degree histogram ----------------
__global__ __launch_bounds__(256) void k_count(const int* __restrict__ dst,
                                               int* __restrict__ degI) {
    int e = blockIdx.x * 256 + threadIdx.x;
    if (e < N_EDGES) atomicAdd(&degI[dst[e]], 1);
}

// ---------------- k_scan: exclusive scan of degI -> offsets (single block) ----------------
__global__ __launch_bounds__(SCAN_T) void k_scan(const int* __restrict__ degI,
                                                 int* __restrict__ offsets) {
    __shared__ int sums[SCAN_T];
    int t = threadIdx.x;
    const int CH = (N_NODES + SCAN_T - 1) / SCAN_T;   // 49
    int base = t * CH;
    int local = 0;
    for (int i = 0; i < CH; ++i) {
        int idx = base + i;
        if (idx < N_NODES) local += degI[idx];
    }
    sums[t] = local;
    __syncthreads();
    // Hillis-Steele inclusive scan in LDS
    for (int off = 1; off < SCAN_T; off <<= 1) {
        int v = (t >= off) ? sums[t - off] : 0;
        __syncthreads();
        sums[t] += v;
        __syncthreads();
    }
    int run = (t == 0) ? 0 : sums[t - 1];
    for (int i = 0; i < CH; ++i) {
        int idx = base + i;
        if (idx < N_NODES) { offsets[idx] = run; run += degI[idx]; }
    }
    if (t == 0) offsets[N_NODES] = sums[SCAN_T - 1];
}

// ---------------- k_fill: scatter edges into CSR slots ----------------
__global__ __launch_bounds__(256) void k_fill(const int* __restrict__ src,
                                              const int* __restrict__ dst,
                                              const float* __restrict__ efeat,
                                              const int* __restrict__ offsets,
                                              int* __restrict__ cursor,
                                              int* __restrict__ csr_src,
                                              float* __restrict__ csr_w) {
    int e = blockIdx.x * 256 + threadIdx.x;
    if (e < N_EDGES) {
        int d = dst[e];
        int pos = offsets[d] + atomicAdd(&cursor[d], 1);
        csr_src[pos] = src[e];
        csr_w[pos]   = efeat[e];
    }
}

// ---------------- k_gather: one wave (64 lanes) per node ----------------
// wsum = sum w; m = exp(-w/wsum); aggF[n] = sum m*feat[src]; msum[n] = sum m
__global__ __launch_bounds__(256) void k_gather(const int* __restrict__ offsets,
                                                const int* __restrict__ csr_src,
                                                const float* __restrict__ csr_w,
                                                const float* __restrict__ feat,
                                                float* __restrict__ msum,
                                                float* __restrict__ aggF) {
    int wid  = (blockIdx.x * 256 + threadIdx.x) >> 6;   // node id
    int lane = threadIdx.x & 63;
    if (wid >= N_NODES) return;
    int beg = offsets[wid], end = offsets[wid + 1];

    float wsum = 0.f;
    for (int j = beg; j < end; ++j) wsum += csr_w[j];   // broadcast loads (same addr all lanes)
    float inv = (end > beg) ? (1.0f / wsum) : 0.0f;

    float2 acc = make_float2(0.f, 0.f);
    float ms = 0.f;
    for (int j = beg; j < end; ++j) {
        int s   = csr_src[j];
        float m = __expf(-csr_w[j] * inv);
        ms += m;
        float2 v = ((const float2*)(feat + (size_t)s * F))[lane];  // 512B/wave coalesced
        acc.x += m * v.x;
        acc.y += m * v.y;
    }
    ((float2*)(aggF + (size_t)wid * F))[lane] = acc;
    if (lane == 0) msum[wid] = ms;
}

// ---------------- Fused dual GEMM + epilogue ----------------
// out[n][o] = dot(feat[n], Ws[o]) + bs[o] + (dot(aggF[n], Wp[o]) + msum[n]*bp[o]) / max(deg[n],1)
__global__ __launch_bounds__(256) void fused_gemm(const float* __restrict__ feat,
                                                  const float* __restrict__ aggF,
                                                  const float* __restrict__ Wp,
                                                  const float* __restrict__ bp,
                                                  const float* __restrict__ Ws,
                                                  const float* __restrict__ bs,
                                                  const float* __restrict__ msum,
                                                  const int* __restrict__ offsets,
                                                  float* __restrict__ out) {
    __shared__ float sF[16][F];
    __shared__ float sA[16][F];
    int t  = threadIdx.x;
    int n0 = blockIdx.x * 16;

    for (int i = t; i < 512; i += 256) {
        int node = i >> 5;
        int c4   = i & 31;
        int gn   = n0 + node;
        float4 f4 = make_float4(0.f, 0.f, 0.f, 0.f);
        float4 a4 = make_float4(0.f, 0.f, 0.f, 0.f);
        if (gn < N_NODES) {
            f4 = ((const float4*)(feat + (size_t)gn * F))[c4];
            a4 = ((const float4*)(aggF + (size_t)gn * F))[c4];
        }
        ((float4*)&sF[node][0])[c4] = f4;
        ((float4*)&sA[node][0])[c4] = a4;
    }
    __syncthreads();

    int cg = t & 63;
    int rg = t >> 6;
    float accS[4][2] = {{0.f,0.f},{0.f,0.f},{0.f,0.f},{0.f,0.f}};
    float accP[4][2] = {{0.f,0.f},{0.f,0.f},{0.f,0.f},{0.f,0.f}};

    const float4* ws0 = (const float4*)(Ws + (size_t)cg * F);
    const float4* ws1 = (const float4*)(Ws + (size_t)(cg + 64) * F);
    const float4* wp0 = (const float4*)(Wp + (size_t)cg * F);
    const float4* wp1 = (const float4*)(Wp + (size_t)(cg + 64) * F);

    #pragma unroll 4
    for (int k4 = 0; k4 < F / 4; ++k4) {
        float4 w0 = ws0[k4], w1 = ws1[k4];
        float4 p0 = wp0[k4], p1 = wp1[k4];
        #pragma unroll
        for (int r = 0; r < 4; ++r) {
            int node = rg + r * 4;
            float4 f = ((const float4*)&sF[node][0])[k4];
            float4 a = ((const float4*)&sA[node][0])[k4];
            accS[r][0] += f.x*w0.x + f.y*w0.y + f.z*w0.z + f.w*w0.w;
            accS[r][1] += f.x*w1.x + f.y*w1.y + f.z*w1.z + f.w*w1.w;
            accP[r][0] += a.x*p0.x + a.y*p0.y + a.z*p0.z + a.w*p0.w;
            accP[r][1] += a.x*p1.x + a.y*p1.y + a.z*p1.z + a.w*p1.w;
        }
    }

    float bs0 = bs[cg], bs1 = bs[cg + 64];
    float bp0 = bp[cg], bp1 = bp[cg + 64];
    #pragma unroll
    for (int r = 0; r < 4; ++r) {
        int gn = n0 + rg + r * 4;
        if (gn >= N_NODES) continue;
        float dv = fmaxf((float)(offsets[gn + 1] - offsets[gn]), 1.0f);
        float ms = msum[gn];
        float inv = 1.0f / dv;
        out[(size_t)gn * F + cg]      = accS[r][0] + bs0 + (accP[r][0] + ms * bp0) * inv;
        out[(size_t)gn * F + cg + 64] = accS[r][1] + bs1 + (accP[r][1] + ms * bp1) * inv;
    }
}

extern "C" void kernel_launch(void* const* d_in, const int* in_sizes, int n_in,
                              void* d_out, int out_size, void* d_ws, size_t ws_size,
                              hipStream_t stream) {
    const float* feat  = (const float*)d_in[0];
    const float* efeat = (const float*)d_in[1];
    const int*   src   = (const int*)d_in[2];
    const int*   dst   = (const int*)d_in[3];
    const float* Wp    = (const float*)d_in[4];
    const float* bp    = (const float*)d_in[5];
    const float* Ws    = (const float*)d_in[6];
    const float* bs    = (const float*)d_in[7];
    float* out = (float*)d_out;

    // workspace layout (4B elems)
    char* p = (char*)d_ws;
    int*   degI    = (int*)p;                     p += (size_t)N_NODES * 4;
    int*   cursor  = (int*)p;                     p += (size_t)N_NODES * 4;
    int*   offsets = (int*)p;                     p += (size_t)(N_NODES + 1) * 4;
    int*   csr_src = (int*)p;                     p += (size_t)N_EDGES * 4;
    float* csr_w   = (float*)p;                   p += (size_t)N_EDGES * 4;
    float* msum    = (float*)p;                   p += (size_t)N_NODES * 4;
    // align aggF to 16B
    p = (char*)(((uintptr_t)p + 15) & ~(uintptr_t)15);
    float* aggF    = (float*)p;

    // zero only degI + cursor (400 KB)
    hipMemsetAsync(d_ws, 0, (size_t)2 * N_NODES * 4, stream);

    k_count<<<(N_EDGES + 255) / 256, 256, 0, stream>>>(dst, degI);
    k_scan<<<1, SCAN_T, 0, stream>>>(degI, offsets);
    k_fill<<<(N_EDGES + 255) / 256, 256, 0, stream>>>(src, dst, efeat, offsets, cursor, csr_src, csr_w);
    k_gather<<<(N_NODES * 64 + 255) / 256, 256, 0, stream>>>(offsets, csr_src, csr_w, feat, msum, aggF);
    fused_gemm<<<(N_NODES + 15) / 16, 256, 0, stream>>>(feat, aggF, Wp, bp, Ws, bs, msum, offsets, out);
}

// Round 4
// 495.747 us; speedup vs baseline: 3.4978x; 1.1707x over previous
//
#include <hip/hip_runtime.h>
#include <hip/hip_bf16.h>

#define N_NODES 50000
#define N_EDGES 800000
#define F 128
#define SCAN_T 1024
#define NT 32   // nodes per block in fused_gemm

// ---------------- k_count: integer degree histogram ----------------
__global__ __launch_bounds__(256) void k_count(const int* __restrict__ dst,
                                               int* __restrict__ degI) {
    int e = blockIdx.x * 256 + threadIdx.x;
    if (e < N_EDGES) atomicAdd(&degI[dst[e]], 1);
}

// ---------------- k_scan: exclusive scan of degI -> offsets (single block) ----------------
__global__ __launch_bounds__(SCAN_T) void k_scan(const int* __restrict__ degI,
                                                 int* __restrict__ offsets) {
    __shared__ int sums[SCAN_T];
    int t = threadIdx.x;
    const int CH = (N_NODES + SCAN_T - 1) / SCAN_T;   // 49
    int base = t * CH;
    int local = 0;
    for (int i = 0; i < CH; ++i) {
        int idx = base + i;
        if (idx < N_NODES) local += degI[idx];
    }
    sums[t] = local;
    __syncthreads();
    for (int off = 1; off < SCAN_T; off <<= 1) {
        int v = (t >= off) ? sums[t - off] : 0;
        __syncthreads();
        sums[t] += v;
        __syncthreads();
    }
    int run = (t == 0) ? 0 : sums[t - 1];
    for (int i = 0; i < CH; ++i) {
        int idx = base + i;
        if (idx < N_NODES) { offsets[idx] = run; run += degI[idx]; }
    }
    if (t == 0) offsets[N_NODES] = sums[SCAN_T - 1];
}

// ---------------- k_fill: scatter edges into CSR slots ----------------
__global__ __launch_bounds__(256) void k_fill(const int* __restrict__ src,
                                              const int* __restrict__ dst,
                                              const float* __restrict__ efeat,
                                              const int* __restrict__ offsets,
                                              int* __restrict__ cursor,
                                              int* __restrict__ csr_src,
                                              float* __restrict__ csr_w) {
    int e = blockIdx.x * 256 + threadIdx.x;
    if (e < N_EDGES) {
        int d = dst[e];
        int pos = offsets[d] + atomicAdd(&cursor[d], 1);
        csr_src[pos] = src[e];
        csr_w[pos]   = efeat[e];
    }
}

// ---------------- k_packW: repack weights k-major interleaved ----------------
// WP[((k>>2)*128 + o)*4 + (k&3)] = W[o*128 + k]
// => per-wave load WsP4[k4*128 + cg] is 64 consecutive float4 = 1KB coalesced.
__global__ __launch_bounds__(256) void k_packW(const float* __restrict__ Wp,
                                               const float* __restrict__ Ws,
                                               float* __restrict__ WpP,
                                               float* __restrict__ WsP) {
    int i = blockIdx.x * 256 + threadIdx.x;   // 16384
    if (i >= F * F) return;
    int o = i >> 7;
    int k = i & 127;
    int d = ((k >> 2) * F + o) * 4 + (k & 3);
    WpP[d] = Wp[i];
    WsP[d] = Ws[i];
}

// ---------------- k_gather: one wave (64 lanes) per node ----------------
__global__ __launch_bounds__(256) void k_gather(const int* __restrict__ offsets,
                                                const int* __restrict__ csr_src,
                                                const float* __restrict__ csr_w,
                                                const float* __restrict__ feat,
                                                float* __restrict__ msum,
                                                float* __restrict__ aggF) {
    int wid  = (blockIdx.x * 256 + threadIdx.x) >> 6;   // node id
    int lane = threadIdx.x & 63;
    if (wid >= N_NODES) return;
    int beg = offsets[wid], end = offsets[wid + 1];

    float wsum = 0.f;
    for (int j = beg; j < end; ++j) wsum += csr_w[j];   // broadcast loads
    float inv = (end > beg) ? (1.0f / wsum) : 0.0f;

    float2 acc = make_float2(0.f, 0.f);
    float ms = 0.f;
    for (int j = beg; j < end; ++j) {
        int s   = csr_src[j];
        float m = __expf(-csr_w[j] * inv);
        ms += m;
        float2 v = ((const float2*)(feat + (size_t)s * F))[lane];  // 512B/wave coalesced
        acc.x += m * v.x;
        acc.y += m * v.y;
    }
    ((float2*)(aggF + (size_t)wid * F))[lane] = acc;
    if (lane == 0) msum[wid] = ms;
}

// ---------------- Fused dual GEMM + epilogue ----------------
// out[n][o] = dot(feat[n], Ws[o]) + bs[o] + (dot(aggF[n], Wp[o]) + msum[n]*bp[o]) / max(deg[n],1)
// Block: 256 threads = 4 waves, NT=32 nodes. Thread: cols {cg, cg+64}, nodes rg+4r (r=0..7).
__global__ __launch_bounds__(256) void fused_gemm(const float* __restrict__ feat,
                                                  const float* __restrict__ aggF,
                                                  const float4* __restrict__ WpP,
                                                  const float* __restrict__ bp,
                                                  const float4* __restrict__ WsP,
                                                  const float* __restrict__ bs,
                                                  const float* __restrict__ msum,
                                                  const int* __restrict__ offsets,
                                                  float* __restrict__ out) {
    __shared__ float sF[NT][F];
    __shared__ float sA[NT][F];
    int t  = threadIdx.x;
    int n0 = blockIdx.x * NT;

    for (int i = t; i < NT * 32; i += 256) {
        int node = i >> 5;
        int c4   = i & 31;
        int gn   = n0 + node;
        float4 f4 = make_float4(0.f, 0.f, 0.f, 0.f);
        float4 a4 = make_float4(0.f, 0.f, 0.f, 0.f);
        if (gn < N_NODES) {
            f4 = ((const float4*)(feat + (size_t)gn * F))[c4];
            a4 = ((const float4*)(aggF + (size_t)gn * F))[c4];
        }
        ((float4*)&sF[node][0])[c4] = f4;
        ((float4*)&sA[node][0])[c4] = a4;
    }
    __syncthreads();

    int cg = t & 63;
    int rg = t >> 6;
    float accS[8][2];
    float accP[8][2];
    #pragma unroll
    for (int r = 0; r < 8; ++r) { accS[r][0]=accS[r][1]=accP[r][0]=accP[r][1]=0.f; }

    #pragma unroll 2
    for (int k4 = 0; k4 < F / 4; ++k4) {
        float4 w0 = WsP[k4 * F + cg];        // 1KB coalesced per wave
        float4 w1 = WsP[k4 * F + cg + 64];
        float4 p0 = WpP[k4 * F + cg];
        float4 p1 = WpP[k4 * F + cg + 64];
        #pragma unroll
        for (int r = 0; r < 8; ++r) {
            int node = rg + r * 4;
            float4 f = ((const float4*)&sF[node][0])[k4];  // LDS broadcast
            float4 a = ((const float4*)&sA[node][0])[k4];
            accS[r][0] += f.x*w0.x + f.y*w0.y + f.z*w0.z + f.w*w0.w;
            accS[r][1] += f.x*w1.x + f.y*w1.y + f.z*w1.z + f.w*w1.w;
            accP[r][0] += a.x*p0.x + a.y*p0.y + a.z*p0.z + a.w*p0.w;
            accP[r][1] += a.x*p1.x + a.y*p1.y + a.z*p1.z + a.w*p1.w;
        }
    }

    float bs0 = bs[cg], bs1 = bs[cg + 64];
    float bp0 = bp[cg], bp1 = bp[cg + 64];
    #pragma unroll
    for (int r = 0; r < 8; ++r) {
        int gn = n0 + rg + r * 4;
        if (gn >= N_NODES) continue;
        float dv = fmaxf((float)(offsets[gn + 1] - offsets[gn]), 1.0f);
        float ms = msum[gn];
        float inv = 1.0f / dv;
        out[(size_t)gn * F + cg]      = accS[r][0] + bs0 + (accP[r][0] + ms * bp0) * inv;
        out[(size_t)gn * F + cg + 64] = accS[r][1] + bs1 + (accP[r][1] + ms * bp1) * inv;
    }
}

extern "C" void kernel_launch(void* const* d_in, const int* in_sizes, int n_in,
                              void* d_out, int out_size, void* d_ws, size_t ws_size,
                              hipStream_t stream) {
    const float* feat  = (const float*)d_in[0];
    const float* efeat = (const float*)d_in[1];
    const int*   src   = (const int*)d_in[2];
    const int*   dst   = (const int*)d_in[3];
    const float* Wp    = (const float*)d_in[4];
    const float* bp    = (const float*)d_in[5];
    const float* Ws    = (const float*)d_in[6];
    const float* bs    = (const float*)d_in[7];
    float* out = (float*)d_out;

    // workspace layout (4B elems)
    char* p = (char*)d_ws;
    int*   degI    = (int*)p;                     p += (size_t)N_NODES * 4;
    int*   cursor  = (int*)p;                     p += (size_t)N_NODES * 4;
    int*   offsets = (int*)p;                     p += (size_t)(N_NODES + 1) * 4;
    int*   csr_src = (int*)p;                     p += (size_t)N_EDGES * 4;
    float* csr_w   = (float*)p;                   p += (size_t)N_EDGES * 4;
    float* msum    = (float*)p;                   p += (size_t)N_NODES * 4;
    p = (char*)(((uintptr_t)p + 15) & ~(uintptr_t)15);
    float* WpP     = (float*)p;                   p += (size_t)F * F * 4;
    float* WsP     = (float*)p;                   p += (size_t)F * F * 4;
    float* aggF    = (float*)p;

    // zero only degI + cursor (400 KB)
    hipMemsetAsync(d_ws, 0, (size_t)2 * N_NODES * 4, stream);

    k_count<<<(N_EDGES + 255) / 256, 256, 0, stream>>>(dst, degI);
    k_packW<<<(F * F + 255) / 256, 256, 0, stream>>>(Wp, Ws, WpP, WsP);
    k_scan<<<1, SCAN_T, 0, stream>>>(degI, offsets);
    k_fill<<<(N_EDGES + 255) / 256, 256, 0, stream>>>(src, dst, efeat, offsets, cursor, csr_src, csr_w);
    k_gather<<<(N_NODES * 64 + 255) / 256, 256, 0, stream>>>(offsets, csr_src, csr_w, feat, msum, aggF);
    fused_gemm<<<(N_NODES + NT - 1) / NT, 256, 0, stream>>>(feat, aggF, (const float4*)WpP, bp,
                                                            (const float4*)WsP, bs, msum, offsets, out);
}

// Round 5
// 425.053 us; speedup vs baseline: 4.0796x; 1.1663x over previous
//
#include <hip/hip_runtime.h>
#include <hip/hip_bf16.h>

#define N_NODES 50000
#define N_EDGES 800000
#define F 128
#define SCAN_T 1024
#define PAD_ROWS 64   // tail-tile slack for fused_gemm A-loads

typedef _Float16 half8 __attribute__((ext_vector_type(8)));
typedef _Float16 half2v __attribute__((ext_vector_type(2)));
typedef float floatx4 __attribute__((ext_vector_type(4)));

// ---------------- k_count: integer degree histogram ----------------
__global__ __launch_bounds__(256) void k_count(const int* __restrict__ dst,
                                               int* __restrict__ degI) {
    int e = blockIdx.x * 256 + threadIdx.x;
    if (e < N_EDGES) atomicAdd(&degI[dst[e]], 1);
}

// ---------------- k_half: fp32 -> fp16 conversion (8 elems/thread) ----------------
__global__ __launch_bounds__(256) void k_half(const float* __restrict__ in,
                                              _Float16* __restrict__ out16, int n8) {
    int i = blockIdx.x * 256 + threadIdx.x;
    if (i >= n8) return;
    const float4* p = (const float4*)in + (size_t)i * 2;
    float4 a = p[0], b = p[1];
    half8 h;
    h[0] = (_Float16)a.x; h[1] = (_Float16)a.y; h[2] = (_Float16)a.z; h[3] = (_Float16)a.w;
    h[4] = (_Float16)b.x; h[5] = (_Float16)b.y; h[6] = (_Float16)b.z; h[7] = (_Float16)b.w;
    ((half8*)out16)[i] = h;
}

// ---------------- k_scan: exclusive scan of degI -> offsets (single block) ----------------
__global__ __launch_bounds__(SCAN_T) void k_scan(const int* __restrict__ degI,
                                                 int* __restrict__ offsets) {
    __shared__ int sums[SCAN_T];
    int t = threadIdx.x;
    const int CH = (N_NODES + SCAN_T - 1) / SCAN_T;   // 49
    int base = t * CH;
    int local = 0;
    for (int i = 0; i < CH; ++i) {
        int idx = base + i;
        if (idx < N_NODES) local += degI[idx];
    }
    sums[t] = local;
    __syncthreads();
    for (int off = 1; off < SCAN_T; off <<= 1) {
        int v = (t >= off) ? sums[t - off] : 0;
        __syncthreads();
        sums[t] += v;
        __syncthreads();
    }
    int run = (t == 0) ? 0 : sums[t - 1];
    for (int i = 0; i < CH; ++i) {
        int idx = base + i;
        if (idx < N_NODES) { offsets[idx] = run; run += degI[idx]; }
    }
    if (t == 0) offsets[N_NODES] = sums[SCAN_T - 1];
}

// ---------------- k_fill: scatter edges into CSR slots (single int2 store) ----------------
__global__ __launch_bounds__(256) void k_fill(const int* __restrict__ src,
                                              const int* __restrict__ dst,
                                              const float* __restrict__ efeat,
                                              const int* __restrict__ offsets,
                                              int* __restrict__ cursor,
                                              int2* __restrict__ csr_sw) {
    int e = blockIdx.x * 256 + threadIdx.x;
    if (e < N_EDGES) {
        int d = dst[e];
        int pos = offsets[d] + atomicAdd(&cursor[d], 1);
        csr_sw[pos] = make_int2(src[e], __float_as_int(efeat[e]));
    }
}

// ---------------- k_gather: one wave per node, fp16 feature gather ----------------
// wsum = sum w; m = exp(-w/wsum); aggH[n] = fp16(sum m*featH[src]); msum[n] = sum m
__global__ __launch_bounds__(256) void k_gather(const int* __restrict__ offsets,
                                                const int2* __restrict__ csr_sw,
                                                const _Float16* __restrict__ featH,
                                                float* __restrict__ msum,
                                                _Float16* __restrict__ aggH) {
    int wid  = (blockIdx.x * 256 + threadIdx.x) >> 6;   // node id
    int lane = threadIdx.x & 63;
    if (wid >= N_NODES) return;
    int beg = offsets[wid], end = offsets[wid + 1];

    float wsum = 0.f;
    for (int j = beg; j < end; ++j) wsum += __int_as_float(csr_sw[j].y);  // broadcast
    float inv = (end > beg) ? (1.0f / wsum) : 0.0f;

    float2 acc = make_float2(0.f, 0.f);
    float ms = 0.f;
    for (int j = beg; j < end; ++j) {
        int2 e = csr_sw[j];
        float m = __expf(-__int_as_float(e.y) * inv);
        ms += m;
        half2v v = ((const half2v*)(featH + (size_t)e.x * F))[lane];  // 256B/wave coalesced
        acc.x += m * (float)v[0];
        acc.y += m * (float)v[1];
    }
    half2v o;
    o[0] = (_Float16)acc.x;
    o[1] = (_Float16)acc.y;
    ((half2v*)(aggH + (size_t)wid * F))[lane] = o;
    if (lane == 0) msum[wid] = ms;
}

// ---------------- fused_gemm: dual MFMA GEMM + epilogue ----------------
// out[n][o] = dot(feat[n],Ws[o]) + bs[o] + (dot(aggF[n],Wp[o]) + msum[n]*bp[o]) / max(deg,1)
// 4 waves/block, 16 nodes/wave (64 nodes/block). Per wave: 8 col-tiles x 4 K-steps x 2 gemms.
// A-frag: A[m=lane&15][k=quad*8+j] -> 16B load from featH/aggH row. B-frag: 16B load from W[o][k] row.
// D: col=lane&15, row=quad*4+reg (m89-verified).
__global__ __launch_bounds__(256) void fused_gemm(const _Float16* __restrict__ featH,
                                                  const _Float16* __restrict__ aggH,
                                                  const _Float16* __restrict__ WpH,
                                                  const float* __restrict__ bp,
                                                  const _Float16* __restrict__ WsH,
                                                  const float* __restrict__ bs,
                                                  const float* __restrict__ msum,
                                                  const int* __restrict__ offsets,
                                                  float* __restrict__ out) {
    int t    = threadIdx.x;
    int wv   = t >> 6;
    int lane = t & 63;
    int n0   = blockIdx.x * 64 + wv * 16;
    if (n0 >= N_NODES) return;          // wave-uniform
    int lrow = lane & 15;
    int quad = lane >> 4;

    floatx4 accS[8], accP[8];
    #pragma unroll
    for (int c = 0; c < 8; ++c) {
        accS[c] = (floatx4){0.f, 0.f, 0.f, 0.f};
        accP[c] = (floatx4){0.f, 0.f, 0.f, 0.f};
    }

    const _Float16* fr  = featH + (size_t)(n0 + lrow) * F + quad * 8;
    const _Float16* ar  = aggH  + (size_t)(n0 + lrow) * F + quad * 8;
    const _Float16* wsr = WsH   + (size_t)lrow * F + quad * 8;
    const _Float16* wpr = WpH   + (size_t)lrow * F + quad * 8;

    #pragma unroll
    for (int kt = 0; kt < 4; ++kt) {
        half8 aF = *(const half8*)(fr + kt * 32);
        half8 aA = *(const half8*)(ar + kt * 32);
        #pragma unroll
        for (int ct = 0; ct < 8; ++ct) {
            half8 bS = *(const half8*)(wsr + (size_t)ct * 16 * F + kt * 32);
            half8 bP = *(const half8*)(wpr + (size_t)ct * 16 * F + kt * 32);
            accS[ct] = __builtin_amdgcn_mfma_f32_16x16x32_f16(aF, bS, accS[ct], 0, 0, 0);
            accP[ct] = __builtin_amdgcn_mfma_f32_16x16x32_f16(aA, bP, accP[ct], 0, 0, 0);
        }
    }

    float ms[4], inv[4];
    int gn[4];
    #pragma unroll
    for (int r = 0; r < 4; ++r) {
        int g = n0 + quad * 4 + r;
        gn[r] = g;
        bool ok = g < N_NODES;
        ms[r]  = ok ? msum[g] : 0.f;
        float dv = ok ? fmaxf((float)(offsets[g + 1] - offsets[g]), 1.0f) : 1.0f;
        inv[r] = 1.0f / dv;
    }
    #pragma unroll
    for (int ct = 0; ct < 8; ++ct) {
        int c = ct * 16 + lrow;
        float bsv = bs[c], bpv = bp[c];
        #pragma unroll
        for (int r = 0; r < 4; ++r) {
            if (gn[r] < N_NODES)
                out[(size_t)gn[r] * F + c] = accS[ct][r] + bsv + (accP[ct][r] + ms[r] * bpv) * inv[r];
        }
    }
}

static inline char* align16(char* p) {
    return (char*)(((uintptr_t)p + 15) & ~(uintptr_t)15);
}

extern "C" void kernel_launch(void* const* d_in, const int* in_sizes, int n_in,
                              void* d_out, int out_size, void* d_ws, size_t ws_size,
                              hipStream_t stream) {
    const float* feat  = (const float*)d_in[0];
    const float* efeat = (const float*)d_in[1];
    const int*   src   = (const int*)d_in[2];
    const int*   dst   = (const int*)d_in[3];
    const float* Wp    = (const float*)d_in[4];
    const float* bp    = (const float*)d_in[5];
    const float* Ws    = (const float*)d_in[6];
    const float* bs    = (const float*)d_in[7];
    float* out = (float*)d_out;

    // workspace layout
    char* p = (char*)d_ws;
    int*      degI    = (int*)p;       p += (size_t)N_NODES * 4;            p = align16(p);
    int*      cursor  = (int*)p;       p += (size_t)N_NODES * 4;            p = align16(p);
    int*      offsets = (int*)p;       p += (size_t)(N_NODES + 1) * 4;      p = align16(p);
    int2*     csr_sw  = (int2*)p;      p += (size_t)N_EDGES * 8;            p = align16(p);
    float*    msum    = (float*)p;     p += (size_t)N_NODES * 4;            p = align16(p);
    _Float16* featH   = (_Float16*)p;  p += (size_t)(N_NODES + PAD_ROWS) * F * 2; p = align16(p);
    _Float16* aggH    = (_Float16*)p;  p += (size_t)(N_NODES + PAD_ROWS) * F * 2; p = align16(p);
    _Float16* WsH     = (_Float16*)p;  p += (size_t)F * F * 2;              p = align16(p);
    _Float16* WpH     = (_Float16*)p;

    // zero degI + cursor (contiguous at base: 2*200000 bytes, degI block is 16-aligned size)
    hipMemsetAsync(d_ws, 0, (size_t)2 * N_NODES * 4, stream);

    k_count<<<(N_EDGES + 255) / 256, 256, 0, stream>>>(dst, degI);
    k_half<<<(N_NODES * F / 8 + 255) / 256, 256, 0, stream>>>(feat, featH, N_NODES * F / 8);
    k_half<<<(F * F / 8 + 255) / 256, 256, 0, stream>>>(Ws, WsH, F * F / 8);
    k_half<<<(F * F / 8 + 255) / 256, 256, 0, stream>>>(Wp, WpH, F * F / 8);
    k_scan<<<1, SCAN_T, 0, stream>>>(degI, offsets);
    k_fill<<<(N_EDGES + 255) / 256, 256, 0, stream>>>(src, dst, efeat, offsets, cursor, csr_sw);
    k_gather<<<(N_NODES * 64 + 255) / 256, 256, 0, stream>>>(offsets, csr_sw, featH, msum, aggH);
    fused_gemm<<<(N_NODES + 63) / 64, 256, 0, stream>>>(featH, aggH, WpH, bp, WsH, bs, msum, offsets, out);
}

// Round 6
// 347.319 us; speedup vs baseline: 4.9926x; 1.2238x over previous
//
#include <hip/hip_runtime.h>
#include <hip/hip_bf16.h>

#define N_NODES 50000
#define N_EDGES 800000
#define F 128
#define SCAN_T 1024
#define PAD_ROWS 64   // tail-tile slack for fused_gemm A-loads

typedef _Float16 half8 __attribute__((ext_vector_type(8)));
typedef _Float16 half2v __attribute__((ext_vector_type(2)));
typedef float floatx4 __attribute__((ext_vector_type(4)));

__device__ inline float wave_sum(float v) {
    #pragma unroll
    for (int o = 32; o > 0; o >>= 1) v += __shfl_xor(v, o);
    return v;
}

// ---------------- k_count: integer degree histogram ----------------
__global__ __launch_bounds__(256) void k_count(const int* __restrict__ dst,
                                               int* __restrict__ degI) {
    int e = blockIdx.x * 256 + threadIdx.x;
    if (e < N_EDGES) atomicAdd(&degI[dst[e]], 1);
}

// ---------------- k_half: fp32 -> fp16 conversion (8 elems/thread) ----------------
__global__ __launch_bounds__(256) void k_half(const float* __restrict__ in,
                                              _Float16* __restrict__ out16, int n8) {
    int i = blockIdx.x * 256 + threadIdx.x;
    if (i >= n8) return;
    const float4* p = (const float4*)in + (size_t)i * 2;
    float4 a = p[0], b = p[1];
    half8 h;
    h[0] = (_Float16)a.x; h[1] = (_Float16)a.y; h[2] = (_Float16)a.z; h[3] = (_Float16)a.w;
    h[4] = (_Float16)b.x; h[5] = (_Float16)b.y; h[6] = (_Float16)b.z; h[7] = (_Float16)b.w;
    ((half8*)out16)[i] = h;
}

// ---------------- k_scan: exclusive scan of degI -> offsets (single block) ----------------
__global__ __launch_bounds__(SCAN_T) void k_scan(const int* __restrict__ degI,
                                                 int* __restrict__ offsets) {
    __shared__ int sums[SCAN_T];
    int t = threadIdx.x;
    const int CH = (N_NODES + SCAN_T - 1) / SCAN_T;   // 49
    int base = t * CH;
    int local = 0;
    for (int i = 0; i < CH; ++i) {
        int idx = base + i;
        if (idx < N_NODES) local += degI[idx];
    }
    sums[t] = local;
    __syncthreads();
    for (int off = 1; off < SCAN_T; off <<= 1) {
        int v = (t >= off) ? sums[t - off] : 0;
        __syncthreads();
        sums[t] += v;
        __syncthreads();
    }
    int run = (t == 0) ? 0 : sums[t - 1];
    for (int i = 0; i < CH; ++i) {
        int idx = base + i;
        if (idx < N_NODES) { offsets[idx] = run; run += degI[idx]; }
    }
    if (t == 0) offsets[N_NODES] = sums[SCAN_T - 1];
}

// ---------------- k_fill: scatter edges into CSR slots (single int2 store) ----------------
__global__ __launch_bounds__(256) void k_fill(const int* __restrict__ src,
                                              const int* __restrict__ dst,
                                              const float* __restrict__ efeat,
                                              const int* __restrict__ offsets,
                                              int* __restrict__ cursor,
                                              int2* __restrict__ csr_sw) {
    int e = blockIdx.x * 256 + threadIdx.x;
    if (e < N_EDGES) {
        int d = dst[e];
        int pos = offsets[d] + atomicAdd(&cursor[d], 1);
        csr_sw[pos] = make_int2(src[e], __float_as_int(efeat[e]));
    }
}

// ---------------- k_gather: one wave per node, 4 edges in flight ----------------
// Per 64-edge chunk: lane j-beg holds (src,w); wsum via wave-reduce; then 4 groups
// of 16 lanes each fetch a full 256B feat row (half8/lane), m/src via __shfl.
__global__ __launch_bounds__(256) void k_gather(const int* __restrict__ offsets,
                                                const int2* __restrict__ csr_sw,
                                                const _Float16* __restrict__ featH,
                                                float* __restrict__ msum,
                                                _Float16* __restrict__ aggH) {
    int wid  = (blockIdx.x * 256 + threadIdx.x) >> 6;   // node id
    int lane = threadIdx.x & 63;
    if (wid >= N_NODES) return;
    int beg = offsets[wid], end = offsets[wid + 1];
    int grp = lane >> 4;        // 0..3
    int lig = lane & 15;        // lane in group

    // pass 1: wsum (parallel + wave reduce)
    float wsum = 0.f;
    for (int c = beg; c < end; c += 64) {
        int j = c + lane;
        wsum += (j < end) ? __int_as_float(csr_sw[j].y) : 0.f;
    }
    wsum = wave_sum(wsum);
    float inv = (end > beg) ? (1.0f / wsum) : 0.0f;

    float acc[8];
    #pragma unroll
    for (int k = 0; k < 8; ++k) acc[k] = 0.f;
    float msacc = 0.f;

    for (int c = beg; c < end; c += 64) {
        int j = c + lane;
        int cnt = end - c; if (cnt > 64) cnt = 64;
        int2 e = (j < end) ? csr_sw[j] : make_int2(0, 0);
        float m = (j < end) ? __expf(-__int_as_float(e.y) * inv) : 0.f;
        msacc += m;
        for (int it = 0; it < cnt; it += 4) {
            int idx  = it + grp;                 // edge slot within chunk for this group
            float mg = __shfl(m, idx);
            int   sg = __shfl(e.x, idx);
            if (idx < cnt) {
                half8 v = *(const half8*)(featH + (size_t)sg * F + lig * 8);
                #pragma unroll
                for (int k = 0; k < 8; ++k) acc[k] += mg * (float)v[k];
            }
        }
    }

    // combine the 4 groups (lanes lig, lig+16, lig+32, lig+48)
    #pragma unroll
    for (int k = 0; k < 8; ++k) {
        acc[k] += __shfl_xor(acc[k], 16);
        acc[k] += __shfl_xor(acc[k], 32);
    }
    msacc = wave_sum(msacc);

    if (grp == 0) {
        half8 o;
        #pragma unroll
        for (int k = 0; k < 8; ++k) o[k] = (_Float16)acc[k];
        ((half8*)(aggH + (size_t)wid * F))[lig] = o;
    }
    if (lane == 0) msum[wid] = msacc;
}

// ---------------- fused_gemm: dual MFMA GEMM + epilogue ----------------
__global__ __launch_bounds__(256) void fused_gemm(const _Float16* __restrict__ featH,
                                                  const _Float16* __restrict__ aggH,
                                                  const _Float16* __restrict__ WpH,
                                                  const float* __restrict__ bp,
                                                  const _Float16* __restrict__ WsH,
                                                  const float* __restrict__ bs,
                                                  const float* __restrict__ msum,
                                                  const int* __restrict__ offsets,
                                                  float* __restrict__ out) {
    int t    = threadIdx.x;
    int wv   = t >> 6;
    int lane = t & 63;
    int n0   = blockIdx.x * 64 + wv * 16;
    if (n0 >= N_NODES) return;          // wave-uniform
    int lrow = lane & 15;
    int quad = lane >> 4;

    floatx4 accS[8], accP[8];
    #pragma unroll
    for (int c = 0; c < 8; ++c) {
        accS[c] = (floatx4){0.f, 0.f, 0.f, 0.f};
        accP[c] = (floatx4){0.f, 0.f, 0.f, 0.f};
    }

    const _Float16* fr  = featH + (size_t)(n0 + lrow) * F + quad * 8;
    const _Float16* ar  = aggH  + (size_t)(n0 + lrow) * F + quad * 8;
    const _Float16* wsr = WsH   + (size_t)lrow * F + quad * 8;
    const _Float16* wpr = WpH   + (size_t)lrow * F + quad * 8;

    #pragma unroll
    for (int kt = 0; kt < 4; ++kt) {
        half8 aF = *(const half8*)(fr + kt * 32);
        half8 aA = *(const half8*)(ar + kt * 32);
        #pragma unroll
        for (int ct = 0; ct < 8; ++ct) {
            half8 bS = *(const half8*)(wsr + (size_t)ct * 16 * F + kt * 32);
            half8 bP = *(const half8*)(wpr + (size_t)ct * 16 * F + kt * 32);
            accS[ct] = __builtin_amdgcn_mfma_f32_16x16x32_f16(aF, bS, accS[ct], 0, 0, 0);
            accP[ct] = __builtin_amdgcn_mfma_f32_16x16x32_f16(aA, bP, accP[ct], 0, 0, 0);
        }
    }

    float ms[4], inv[4];
    int gn[4];
    #pragma unroll
    for (int r = 0; r < 4; ++r) {
        int g = n0 + quad * 4 + r;
        gn[r] = g;
        bool ok = g < N_NODES;
        ms[r]  = ok ? msum[g] : 0.f;
        float dv = ok ? fmaxf((float)(offsets[g + 1] - offsets[g]), 1.0f) : 1.0f;
        inv[r] = 1.0f / dv;
    }
    #pragma unroll
    for (int ct = 0; ct < 8; ++ct) {
        int c = ct * 16 + lrow;
        float bsv = bs[c], bpv = bp[c];
        #pragma unroll
        for (int r = 0; r < 4; ++r) {
            if (gn[r] < N_NODES)
                out[(size_t)gn[r] * F + c] = accS[ct][r] + bsv + (accP[ct][r] + ms[r] * bpv) * inv[r];
        }
    }
}

static inline char* align16(char* p) {
    return (char*)(((uintptr_t)p + 15) & ~(uintptr_t)15);
}

extern "C" void kernel_launch(void* const* d_in, const int* in_sizes, int n_in,
                              void* d_out, int out_size, void* d_ws, size_t ws_size,
                              hipStream_t stream) {
    const float* feat  = (const float*)d_in[0];
    const float* efeat = (const float*)d_in[1];
    const int*   src   = (const int*)d_in[2];
    const int*   dst   = (const int*)d_in[3];
    const float* Wp    = (const float*)d_in[4];
    const float* bp    = (const float*)d_in[5];
    const float* Ws    = (const float*)d_in[6];
    const float* bs    = (const float*)d_in[7];
    float* out = (float*)d_out;

    // workspace layout
    char* p = (char*)d_ws;
    int*      degI    = (int*)p;       p += (size_t)N_NODES * 4;            p = align16(p);
    int*      cursor  = (int*)p;       p += (size_t)N_NODES * 4;            p = align16(p);
    int*      offsets = (int*)p;       p += (size_t)(N_NODES + 1) * 4;      p = align16(p);
    int2*     csr_sw  = (int2*)p;      p += (size_t)N_EDGES * 8;            p = align16(p);
    float*    msum    = (float*)p;     p += (size_t)N_NODES * 4;            p = align16(p);
    _Float16* featH   = (_Float16*)p;  p += (size_t)(N_NODES + PAD_ROWS) * F * 2; p = align16(p);
    _Float16* aggH    = (_Float16*)p;  p += (size_t)(N_NODES + PAD_ROWS) * F * 2; p = align16(p);
    _Float16* WsH     = (_Float16*)p;  p += (size_t)F * F * 2;              p = align16(p);
    _Float16* WpH     = (_Float16*)p;

    // zero degI + cursor
    hipMemsetAsync(d_ws, 0, (size_t)2 * N_NODES * 4, stream);

    k_count<<<(N_EDGES + 255) / 256, 256, 0, stream>>>(dst, degI);
    k_half<<<(N_NODES * F / 8 + 255) / 256, 256, 0, stream>>>(feat, featH, N_NODES * F / 8);
    k_half<<<(F * F / 8 + 255) / 256, 256, 0, stream>>>(Ws, WsH, F * F / 8);
    k_half<<<(F * F / 8 + 255) / 256, 256, 0, stream>>>(Wp, WpH, F * F / 8);
    k_scan<<<1, SCAN_T, 0, stream>>>(degI, offsets);
    k_fill<<<(N_EDGES + 255) / 256, 256, 0, stream>>>(src, dst, efeat, offsets, cursor, csr_sw);
    k_gather<<<(N_NODES * 64 + 255) / 256, 256, 0, stream>>>(offsets, csr_sw, featH, msum, aggH);
    fused_gemm<<<(N_NODES + 63) / 64, 256, 0, stream>>>(featH, aggH, WpH, bp, WsH, bs, msum, offsets, out);
}

// Round 7
// 243.519 us; speedup vs baseline: 7.1207x; 1.4263x over previous
//
#include <hip/hip_runtime.h>
#include <hip/hip_bf16.h>

#define N_NODES 50000
#define N_EDGES 800000
#define F 128
#define PAD_ROWS 64   // tail-tile slack for fused_gemm A-loads
#define SCAN_BLK 256
#define SCAN_NB ((N_NODES + SCAN_BLK - 1) / SCAN_BLK)   // 196

typedef _Float16 half8 __attribute__((ext_vector_type(8)));
typedef float floatx4 __attribute__((ext_vector_type(4)));

__device__ inline float wave_sum(float v) {
    #pragma unroll
    for (int o = 32; o > 0; o >>= 1) v += __shfl_xor(v, o);
    return v;
}

// ---------------- k_count: degree histogram + per-edge rank ----------------
__global__ __launch_bounds__(256) void k_count(const int* __restrict__ dst,
                                               int* __restrict__ degI,
                                               int* __restrict__ rank) {
    int e = blockIdx.x * 256 + threadIdx.x;
    if (e < N_EDGES) rank[e] = atomicAdd(&degI[dst[e]], 1);
}

// ---------------- k_half: fp32 -> fp16 conversion (8 elems/thread) ----------------
__global__ __launch_bounds__(256) void k_half(const float* __restrict__ in,
                                              _Float16* __restrict__ out16, int n8) {
    int i = blockIdx.x * 256 + threadIdx.x;
    if (i >= n8) return;
    const float4* p = (const float4*)in + (size_t)i * 2;
    float4 a = p[0], b = p[1];
    half8 h;
    h[0] = (_Float16)a.x; h[1] = (_Float16)a.y; h[2] = (_Float16)a.z; h[3] = (_Float16)a.w;
    h[4] = (_Float16)b.x; h[5] = (_Float16)b.y; h[6] = (_Float16)b.z; h[7] = (_Float16)b.w;
    ((half8*)out16)[i] = h;
}

// ---------------- k_halfW: both weight matrices in one launch ----------------
__global__ __launch_bounds__(256) void k_halfW(const float* __restrict__ Wp,
                                               const float* __restrict__ Ws,
                                               _Float16* __restrict__ WpH,
                                               _Float16* __restrict__ WsH) {
    int i = blockIdx.x * 256 + threadIdx.x;   // F*F/8 = 2048
    if (i >= F * F / 8) return;
    const float4* pp = (const float4*)Wp + (size_t)i * 2;
    const float4* ps = (const float4*)Ws + (size_t)i * 2;
    float4 a = pp[0], b = pp[1];
    half8 h;
    h[0]=(_Float16)a.x; h[1]=(_Float16)a.y; h[2]=(_Float16)a.z; h[3]=(_Float16)a.w;
    h[4]=(_Float16)b.x; h[5]=(_Float16)b.y; h[6]=(_Float16)b.z; h[7]=(_Float16)b.w;
    ((half8*)WpH)[i] = h;
    a = ps[0]; b = ps[1];
    h[0]=(_Float16)a.x; h[1]=(_Float16)a.y; h[2]=(_Float16)a.z; h[3]=(_Float16)a.w;
    h[4]=(_Float16)b.x; h[5]=(_Float16)b.y; h[6]=(_Float16)b.z; h[7]=(_Float16)b.w;
    ((half8*)WsH)[i] = h;
}

// ---------------- parallel 3-phase exclusive scan ----------------
__global__ __launch_bounds__(SCAN_BLK) void k_scan1(const int* __restrict__ degI,
                                                    int* __restrict__ blockSums) {
    __shared__ int s[SCAN_BLK];
    int t = threadIdx.x;
    int i = blockIdx.x * SCAN_BLK + t;
    s[t] = (i < N_NODES) ? degI[i] : 0;
    __syncthreads();
    for (int o = SCAN_BLK / 2; o > 0; o >>= 1) {
        if (t < o) s[t] += s[t + o];
        __syncthreads();
    }
    if (t == 0) blockSums[blockIdx.x] = s[0];
}

__global__ __launch_bounds__(SCAN_BLK) void k_scan2(int* __restrict__ blockSums,
                                                    int* __restrict__ offsets) {
    __shared__ int s[SCAN_BLK];
    int t = threadIdx.x;
    int v = (t < SCAN_NB) ? blockSums[t] : 0;
    s[t] = v;
    __syncthreads();
    for (int o = 1; o < SCAN_BLK; o <<= 1) {
        int u = (t >= o) ? s[t - o] : 0;
        __syncthreads();
        s[t] += u;
        __syncthreads();
    }
    if (t < SCAN_NB) blockSums[t] = s[t] - v;   // exclusive prefix, in place
    if (t == 0) offsets[N_NODES] = N_EDGES;
}

__global__ __launch_bounds__(SCAN_BLK) void k_scan3(const int* __restrict__ degI,
                                                    const int* __restrict__ blockSums,
                                                    int* __restrict__ offsets) {
    __shared__ int s[SCAN_BLK];
    int t = threadIdx.x;
    int i = blockIdx.x * SCAN_BLK + t;
    int v = (i < N_NODES) ? degI[i] : 0;
    s[t] = v;
    __syncthreads();
    for (int o = 1; o < SCAN_BLK; o <<= 1) {
        int u = (t >= o) ? s[t - o] : 0;
        __syncthreads();
        s[t] += u;
        __syncthreads();
    }
    if (i < N_NODES) offsets[i] = s[t] - v + blockSums[blockIdx.x];
}

// ---------------- k_fill: CSR scatter, NO atomics (rank precomputed) ----------------
__global__ __launch_bounds__(256) void k_fill(const int* __restrict__ src,
                                              const int* __restrict__ dst,
                                              const float* __restrict__ efeat,
                                              const int* __restrict__ offsets,
                                              const int* __restrict__ rank,
                                              int2* __restrict__ csr_sw) {
    int e = blockIdx.x * 256 + threadIdx.x;
    if (e < N_EDGES) {
        int pos = offsets[dst[e]] + rank[e];
        csr_sw[pos] = make_int2(src[e], __float_as_int(efeat[e]));
    }
}

// ---------------- k_gather: one wave per node, 4 feat rows in flight ----------------
__global__ __launch_bounds__(256) void k_gather(const int* __restrict__ offsets,
                                                const int2* __restrict__ csr_sw,
                                                const _Float16* __restrict__ featH,
                                                float* __restrict__ msum,
                                                _Float16* __restrict__ aggH) {
    int wid  = (blockIdx.x * 256 + threadIdx.x) >> 6;   // node id
    int lane = threadIdx.x & 63;
    if (wid >= N_NODES) return;
    int beg = offsets[wid], end = offsets[wid + 1];
    int grp = lane >> 4;        // 0..3
    int lig = lane & 15;        // lane in group

    float wsum = 0.f;
    for (int c = beg; c < end; c += 64) {
        int j = c + lane;
        wsum += (j < end) ? __int_as_float(csr_sw[j].y) : 0.f;
    }
    wsum = wave_sum(wsum);
    float inv = (end > beg) ? (1.0f / wsum) : 0.0f;

    float acc[8];
    #pragma unroll
    for (int k = 0; k < 8; ++k) acc[k] = 0.f;
    float msacc = 0.f;

    for (int c = beg; c < end; c += 64) {
        int j = c + lane;
        int cnt = end - c; if (cnt > 64) cnt = 64;
        int2 e = (j < end) ? csr_sw[j] : make_int2(0, 0);
        float m = (j < end) ? __expf(-__int_as_float(e.y) * inv) : 0.f;
        msacc += m;
        for (int it = 0; it < cnt; it += 4) {
            int idx  = it + grp;
            float mg = __shfl(m, idx);
            int   sg = __shfl(e.x, idx);
            if (idx < cnt) {
                half8 v = *(const half8*)(featH + (size_t)sg * F + lig * 8);
                #pragma unroll
                for (int k = 0; k < 8; ++k) acc[k] += mg * (float)v[k];
            }
        }
    }

    #pragma unroll
    for (int k = 0; k < 8; ++k) {
        acc[k] += __shfl_xor(acc[k], 16);
        acc[k] += __shfl_xor(acc[k], 32);
    }
    msacc = wave_sum(msacc);

    if (grp == 0) {
        half8 o;
        #pragma unroll
        for (int k = 0; k < 8; ++k) o[k] = (_Float16)acc[k];
        ((half8*)(aggH + (size_t)wid * F))[lig] = o;
    }
    if (lane == 0) msum[wid] = msacc;
}

// ---------------- fused_gemm: dual MFMA GEMM + epilogue ----------------
__global__ __launch_bounds__(256) void fused_gemm(const _Float16* __restrict__ featH,
                                                  const _Float16* __restrict__ aggH,
                                                  const _Float16* __restrict__ WpH,
                                                  const float* __restrict__ bp,
                                                  const _Float16* __restrict__ WsH,
                                                  const float* __restrict__ bs,
                                                  const float* __restrict__ msum,
                                                  const int* __restrict__ offsets,
                                                  float* __restrict__ out) {
    int t    = threadIdx.x;
    int wv   = t >> 6;
    int lane = t & 63;
    int n0   = blockIdx.x * 64 + wv * 16;
    if (n0 >= N_NODES) return;          // wave-uniform
    int lrow = lane & 15;
    int quad = lane >> 4;

    floatx4 accS[8], accP[8];
    #pragma unroll
    for (int c = 0; c < 8; ++c) {
        accS[c] = (floatx4){0.f, 0.f, 0.f, 0.f};
        accP[c] = (floatx4){0.f, 0.f, 0.f, 0.f};
    }

    const _Float16* fr  = featH + (size_t)(n0 + lrow) * F + quad * 8;
    const _Float16* ar  = aggH  + (size_t)(n0 + lrow) * F + quad * 8;
    const _Float16* wsr = WsH   + (size_t)lrow * F + quad * 8;
    const _Float16* wpr = WpH   + (size_t)lrow * F + quad * 8;

    #pragma unroll
    for (int kt = 0; kt < 4; ++kt) {
        half8 aF = *(const half8*)(fr + kt * 32);
        half8 aA = *(const half8*)(ar + kt * 32);
        #pragma unroll
        for (int ct = 0; ct < 8; ++ct) {
            half8 bS = *(const half8*)(wsr + (size_t)ct * 16 * F + kt * 32);
            half8 bP = *(const half8*)(wpr + (size_t)ct * 16 * F + kt * 32);
            accS[ct] = __builtin_amdgcn_mfma_f32_16x16x32_f16(aF, bS, accS[ct], 0, 0, 0);
            accP[ct] = __builtin_amdgcn_mfma_f32_16x16x32_f16(aA, bP, accP[ct], 0, 0, 0);
        }
    }

    float ms[4], inv[4];
    int gn[4];
    #pragma unroll
    for (int r = 0; r < 4; ++r) {
        int g = n0 + quad * 4 + r;
        gn[r] = g;
        bool ok = g < N_NODES;
        ms[r]  = ok ? msum[g] : 0.f;
        float dv = ok ? fmaxf((float)(offsets[g + 1] - offsets[g]), 1.0f) : 1.0f;
        inv[r] = 1.0f / dv;
    }
    #pragma unroll
    for (int ct = 0; ct < 8; ++ct) {
        int c = ct * 16 + lrow;
        float bsv = bs[c], bpv = bp[c];
        #pragma unroll
        for (int r = 0; r < 4; ++r) {
            if (gn[r] < N_NODES)
                out[(size_t)gn[r] * F + c] = accS[ct][r] + bsv + (accP[ct][r] + ms[r] * bpv) * inv[r];
        }
    }
}

static inline char* align16(char* p) {
    return (char*)(((uintptr_t)p + 15) & ~(uintptr_t)15);
}

extern "C" void kernel_launch(void* const* d_in, const int* in_sizes, int n_in,
                              void* d_out, int out_size, void* d_ws, size_t ws_size,
                              hipStream_t stream) {
    const float* feat  = (const float*)d_in[0];
    const float* efeat = (const float*)d_in[1];
    const int*   src   = (const int*)d_in[2];
    const int*   dst   = (const int*)d_in[3];
    const float* Wp    = (const float*)d_in[4];
    const float* bp    = (const float*)d_in[5];
    const float* Ws    = (const float*)d_in[6];
    const float* bs    = (const float*)d_in[7];
    float* out = (float*)d_out;

    // workspace layout
    char* p = (char*)d_ws;
    int*      degI     = (int*)p;      p += (size_t)N_NODES * 4;            p = align16(p);
    int*      offsets  = (int*)p;      p += (size_t)(N_NODES + 1) * 4;      p = align16(p);
    int*      blockSums= (int*)p;      p += (size_t)SCAN_BLK * 4;           p = align16(p);
    int2*     csr_sw   = (int2*)p;     p += (size_t)N_EDGES * 8;            p = align16(p);
    float*    msum     = (float*)p;    p += (size_t)N_NODES * 4;            p = align16(p);
    _Float16* featH    = (_Float16*)p; p += (size_t)(N_NODES + PAD_ROWS) * F * 2; p = align16(p);
    _Float16* aggH     = (_Float16*)p; p += (size_t)(N_NODES + PAD_ROWS) * F * 2; p = align16(p);
    _Float16* WsH      = (_Float16*)p; p += (size_t)F * F * 2;              p = align16(p);
    _Float16* WpH      = (_Float16*)p;
    // rank lives in aggH's region: written by k_count, read by k_fill,
    // both strictly before k_gather writes aggH. 3.2 MB <= 12.8 MB.
    int* rank = (int*)aggH;

    // zero degI only
    hipMemsetAsync(d_ws, 0, (size_t)N_NODES * 4, stream);

    k_count<<<(N_EDGES + 255) / 256, 256, 0, stream>>>(dst, degI, rank);
    k_half<<<(N_NODES * F / 8 + 255) / 256, 256, 0, stream>>>(feat, featH, N_NODES * F / 8);
    k_halfW<<<(F * F / 8 + 255) / 256, 256, 0, stream>>>(Wp, Ws, WpH, WsH);
    k_scan1<<<SCAN_NB, SCAN_BLK, 0, stream>>>(degI, blockSums);
    k_scan2<<<1, SCAN_BLK, 0, stream>>>(blockSums, offsets);
    k_scan3<<<SCAN_NB, SCAN_BLK, 0, stream>>>(degI, blockSums, offsets);
    k_fill<<<(N_EDGES + 255) / 256, 256, 0, stream>>>(src, dst, efeat, offsets, rank, csr_sw);
    k_gather<<<(N_NODES * 64 + 255) / 256, 256, 0, stream>>>(offsets, csr_sw, featH, msum, aggH);
    fused_gemm<<<(N_NODES + 63) / 64, 256, 0, stream>>>(featH, aggH, WpH, bp, WsH, bs, msum, offsets, out);
}

// Round 8
// 208.199 us; speedup vs baseline: 8.3287x; 1.1696x over previous
//
#include <hip/hip_runtime.h>
#include <hip/hip_bf16.h>

#define N_NODES 50000
#define N_EDGES 800000
#define F 128
#define PAD_ROWS 64   // tail-tile slack for fused_gemm A-loads
#define SCAN_BLK 256
#define SCAN_NB ((N_NODES + SCAN_BLK - 1) / SCAN_BLK)   // 196

typedef _Float16 half8 __attribute__((ext_vector_type(8)));
typedef float floatx4 __attribute__((ext_vector_type(4)));

__device__ inline float wave_sum(float v) {
    #pragma unroll
    for (int o = 32; o > 0; o >>= 1) v += __shfl_xor(v, o);
    return v;
}

// ---------------- k_prep: feat->fp16, weights->fp16, degree histogram + rank ----------------
// N_EDGES == N_NODES*F/8 == 800000, so one 800000-thread grid covers all three jobs.
__global__ __launch_bounds__(256) void k_prep(const float* __restrict__ feat,
                                              const float* __restrict__ Wp,
                                              const float* __restrict__ Ws,
                                              const int* __restrict__ dst,
                                              _Float16* __restrict__ featH,
                                              _Float16* __restrict__ WpH,
                                              _Float16* __restrict__ WsH,
                                              int* __restrict__ degI,
                                              int* __restrict__ rank) {
    int i = blockIdx.x * 256 + threadIdx.x;
    if (i < N_NODES * F / 8) {
        const float4* p = (const float4*)feat + (size_t)i * 2;
        float4 a = p[0], b = p[1];
        half8 h;
        h[0]=(_Float16)a.x; h[1]=(_Float16)a.y; h[2]=(_Float16)a.z; h[3]=(_Float16)a.w;
        h[4]=(_Float16)b.x; h[5]=(_Float16)b.y; h[6]=(_Float16)b.z; h[7]=(_Float16)b.w;
        ((half8*)featH)[i] = h;
    }
    if (i < N_EDGES) {
        rank[i] = atomicAdd(&degI[dst[i]], 1);
    }
    if (i < F * F / 8) {
        const float4* pp = (const float4*)Wp + (size_t)i * 2;
        const float4* ps = (const float4*)Ws + (size_t)i * 2;
        float4 a = pp[0], b = pp[1];
        half8 h;
        h[0]=(_Float16)a.x; h[1]=(_Float16)a.y; h[2]=(_Float16)a.z; h[3]=(_Float16)a.w;
        h[4]=(_Float16)b.x; h[5]=(_Float16)b.y; h[6]=(_Float16)b.z; h[7]=(_Float16)b.w;
        ((half8*)WpH)[i] = h;
        a = ps[0]; b = ps[1];
        h[0]=(_Float16)a.x; h[1]=(_Float16)a.y; h[2]=(_Float16)a.z; h[3]=(_Float16)a.w;
        h[4]=(_Float16)b.x; h[5]=(_Float16)b.y; h[6]=(_Float16)b.z; h[7]=(_Float16)b.w;
        ((half8*)WsH)[i] = h;
    }
}

// ---------------- parallel 3-phase exclusive scan ----------------
__global__ __launch_bounds__(SCAN_BLK) void k_scan1(const int* __restrict__ degI,
                                                    int* __restrict__ blockSums) {
    __shared__ int s[SCAN_BLK];
    int t = threadIdx.x;
    int i = blockIdx.x * SCAN_BLK + t;
    s[t] = (i < N_NODES) ? degI[i] : 0;
    __syncthreads();
    for (int o = SCAN_BLK / 2; o > 0; o >>= 1) {
        if (t < o) s[t] += s[t + o];
        __syncthreads();
    }
    if (t == 0) blockSums[blockIdx.x] = s[0];
}

__global__ __launch_bounds__(SCAN_BLK) void k_scan2(int* __restrict__ blockSums,
                                                    int* __restrict__ offsets) {
    __shared__ int s[SCAN_BLK];
    int t = threadIdx.x;
    int v = (t < SCAN_NB) ? blockSums[t] : 0;
    s[t] = v;
    __syncthreads();
    for (int o = 1; o < SCAN_BLK; o <<= 1) {
        int u = (t >= o) ? s[t - o] : 0;
        __syncthreads();
        s[t] += u;
        __syncthreads();
    }
    if (t < SCAN_NB) blockSums[t] = s[t] - v;   // exclusive prefix, in place
    if (t == 0) offsets[N_NODES] = N_EDGES;
}

__global__ __launch_bounds__(SCAN_BLK) void k_scan3(const int* __restrict__ degI,
                                                    const int* __restrict__ blockSums,
                                                    int* __restrict__ offsets) {
    __shared__ int s[SCAN_BLK];
    int t = threadIdx.x;
    int i = blockIdx.x * SCAN_BLK + t;
    int v = (i < N_NODES) ? degI[i] : 0;
    s[t] = v;
    __syncthreads();
    for (int o = 1; o < SCAN_BLK; o <<= 1) {
        int u = (t >= o) ? s[t - o] : 0;
        __syncthreads();
        s[t] += u;
        __syncthreads();
    }
    if (i < N_NODES) offsets[i] = s[t] - v + blockSums[blockIdx.x];
}

// ---------------- k_fill: CSR scatter, NO atomics (rank precomputed) ----------------
__global__ __launch_bounds__(256) void k_fill(const int* __restrict__ src,
                                              const int* __restrict__ dst,
                                              const float* __restrict__ efeat,
                                              const int* __restrict__ offsets,
                                              const int* __restrict__ rank,
                                              int2* __restrict__ csr_sw) {
    int e = blockIdx.x * 256 + threadIdx.x;
    if (e < N_EDGES) {
        int pos = offsets[dst[e]] + rank[e];
        csr_sw[pos] = make_int2(src[e], __float_as_int(efeat[e]));
    }
}

// ---------------- k_gather: one wave per node, 4 feat rows in flight ----------------
__global__ __launch_bounds__(256) void k_gather(const int* __restrict__ offsets,
                                                const int2* __restrict__ csr_sw,
                                                const _Float16* __restrict__ featH,
                                                float* __restrict__ msum,
                                                _Float16* __restrict__ aggH) {
    int wid  = (blockIdx.x * 256 + threadIdx.x) >> 6;   // node id
    int lane = threadIdx.x & 63;
    if (wid >= N_NODES) return;
    int beg = offsets[wid], end = offsets[wid + 1];
    int grp = lane >> 4;        // 0..3
    int lig = lane & 15;        // lane in group

    float wsum = 0.f;
    for (int c = beg; c < end; c += 64) {
        int j = c + lane;
        wsum += (j < end) ? __int_as_float(csr_sw[j].y) : 0.f;
    }
    wsum = wave_sum(wsum);
    float inv = (end > beg) ? (1.0f / wsum) : 0.0f;

    float acc[8];
    #pragma unroll
    for (int k = 0; k < 8; ++k) acc[k] = 0.f;
    float msacc = 0.f;

    for (int c = beg; c < end; c += 64) {
        int j = c + lane;
        int cnt = end - c; if (cnt > 64) cnt = 64;
        int2 e = (j < end) ? csr_sw[j] : make_int2(0, 0);
        float m = (j < end) ? __expf(-__int_as_float(e.y) * inv) : 0.f;
        msacc += m;
        for (int it = 0; it < cnt; it += 4) {
            int idx  = it + grp;
            float mg = __shfl(m, idx);
            int   sg = __shfl(e.x, idx);
            if (idx < cnt) {
                half8 v = *(const half8*)(featH + (size_t)sg * F + lig * 8);
                #pragma unroll
                for (int k = 0; k < 8; ++k) acc[k] += mg * (float)v[k];
            }
        }
    }

    #pragma unroll
    for (int k = 0; k < 8; ++k) {
        acc[k] += __shfl_xor(acc[k], 16);
        acc[k] += __shfl_xor(acc[k], 32);
    }
    msacc = wave_sum(msacc);

    if (grp == 0) {
        half8 o;
        #pragma unroll
        for (int k = 0; k < 8; ++k) o[k] = (_Float16)acc[k];
        ((half8*)(aggH + (size_t)wid * F))[lig] = o;
    }
    if (lane == 0) msum[wid] = msacc;
}

// ---------------- fused_gemm: dual MFMA GEMM, weights staged in LDS ----------------
// 512 threads = 8 waves, 16 nodes/wave -> 128 nodes/block.
// LDS: both weight matrices (32KB each) pre-arranged in B-fragment order:
//   slot (ct*4+kt)*64 + lane holds the 16B that lane needs -> ds_read_b128 conflict-free.
// Chunk c of row-major W (row o=c>>4, halves (c&15)*8) maps to
//   lane=(o&15)|((c&3)<<4), slot=((o>>4)*4+((c&15)>>2))*64+lane; global half8 index == c.
__global__ __launch_bounds__(512, 4) void fused_gemm(const _Float16* __restrict__ featH,
                                                     const _Float16* __restrict__ aggH,
                                                     const _Float16* __restrict__ WpH,
                                                     const float* __restrict__ bp,
                                                     const _Float16* __restrict__ WsH,
                                                     const float* __restrict__ bs,
                                                     const float* __restrict__ msum,
                                                     const int* __restrict__ offsets,
                                                     float* __restrict__ out) {
    __shared__ half8 sBS[2048];   // 32 KB
    __shared__ half8 sBP[2048];   // 32 KB

    int t = threadIdx.x;
    for (int c = t; c < 2048; c += 512) {
        int o  = c >> 4;
        int k8 = c & 15;
        int lane = (o & 15) | ((k8 & 3) << 4);
        int slot = ((o >> 4) * 4 + (k8 >> 2)) * 64 + lane;
        sBS[slot] = ((const half8*)WsH)[c];
        sBP[slot] = ((const half8*)WpH)[c];
    }
    __syncthreads();

    int wv   = t >> 6;
    int lane = t & 63;
    int n0   = blockIdx.x * 128 + wv * 16;   // may exceed N_NODES for tail waves: compute garbage, guard stores
    int lrow = lane & 15;
    int quad = lane >> 4;

    floatx4 accS[8], accP[8];
    #pragma unroll
    for (int c = 0; c < 8; ++c) {
        accS[c] = (floatx4){0.f, 0.f, 0.f, 0.f};
        accP[c] = (floatx4){0.f, 0.f, 0.f, 0.f};
    }

    const half8* fr = (const half8*)(featH + (size_t)(n0 + lrow) * F) + quad;
    const half8* ar = (const half8*)(aggH  + (size_t)(n0 + lrow) * F) + quad;

    #pragma unroll
    for (int kt = 0; kt < 4; ++kt) {
        half8 aF = fr[kt * 4];
        half8 aA = ar[kt * 4];
        #pragma unroll
        for (int ct = 0; ct < 8; ++ct) {
            half8 bS = sBS[(ct * 4 + kt) * 64 + lane];
            half8 bP = sBP[(ct * 4 + kt) * 64 + lane];
            accS[ct] = __builtin_amdgcn_mfma_f32_16x16x32_f16(aF, bS, accS[ct], 0, 0, 0);
            accP[ct] = __builtin_amdgcn_mfma_f32_16x16x32_f16(aA, bP, accP[ct], 0, 0, 0);
        }
    }

    float ms[4], inv[4];
    int gn[4];
    #pragma unroll
    for (int r = 0; r < 4; ++r) {
        int g = n0 + quad * 4 + r;
        gn[r] = g;
        bool ok = g < N_NODES;
        ms[r]  = ok ? msum[g] : 0.f;
        float dv = ok ? fmaxf((float)(offsets[g + 1] - offsets[g]), 1.0f) : 1.0f;
        inv[r] = 1.0f / dv;
    }
    #pragma unroll
    for (int ct = 0; ct < 8; ++ct) {
        int c = ct * 16 + lrow;
        float bsv = bs[c], bpv = bp[c];
        #pragma unroll
        for (int r = 0; r < 4; ++r) {
            if (gn[r] < N_NODES)
                out[(size_t)gn[r] * F + c] = accS[ct][r] + bsv + (accP[ct][r] + ms[r] * bpv) * inv[r];
        }
    }
}

static inline char* align16(char* p) {
    return (char*)(((uintptr_t)p + 15) & ~(uintptr_t)15);
}

extern "C" void kernel_launch(void* const* d_in, const int* in_sizes, int n_in,
                              void* d_out, int out_size, void* d_ws, size_t ws_size,
                              hipStream_t stream) {
    const float* feat  = (const float*)d_in[0];
    const float* efeat = (const float*)d_in[1];
    const int*   src   = (const int*)d_in[2];
    const int*   dst   = (const int*)d_in[3];
    const float* Wp    = (const float*)d_in[4];
    const float* bp    = (const float*)d_in[5];
    const float* Ws    = (const float*)d_in[6];
    const float* bs    = (const float*)d_in[7];
    float* out = (float*)d_out;

    // workspace layout
    char* p = (char*)d_ws;
    int*      degI     = (int*)p;      p += (size_t)N_NODES * 4;            p = align16(p);
    int*      offsets  = (int*)p;      p += (size_t)(N_NODES + 1) * 4;      p = align16(p);
    int*      blockSums= (int*)p;      p += (size_t)SCAN_BLK * 4;           p = align16(p);
    int2*     csr_sw   = (int2*)p;     p += (size_t)N_EDGES * 8;            p = align16(p);
    float*    msum     = (float*)p;    p += (size_t)N_NODES * 4;            p = align16(p);
    _Float16* featH    = (_Float16*)p; p += (size_t)(N_NODES + PAD_ROWS) * F * 2; p = align16(p);
    _Float16* aggH     = (_Float16*)p; p += (size_t)(N_NODES + PAD_ROWS) * F * 2; p = align16(p);
    _Float16* WsH      = (_Float16*)p; p += (size_t)F * F * 2;              p = align16(p);
    _Float16* WpH      = (_Float16*)p;
    // rank lives in aggH's region: written by k_prep, read by k_fill,
    // both strictly before k_gather writes aggH. 3.2 MB <= 12.8 MB.
    int* rank = (int*)aggH;

    // zero degI only
    hipMemsetAsync(d_ws, 0, (size_t)N_NODES * 4, stream);

    k_prep<<<(N_EDGES + 255) / 256, 256, 0, stream>>>(feat, Wp, Ws, dst, featH, WpH, WsH, degI, rank);
    k_scan1<<<SCAN_NB, SCAN_BLK, 0, stream>>>(degI, blockSums);
    k_scan2<<<1, SCAN_BLK, 0, stream>>>(blockSums, offsets);
    k_scan3<<<SCAN_NB, SCAN_BLK, 0, stream>>>(degI, blockSums, offsets);
    k_fill<<<(N_EDGES + 255) / 256, 256, 0, stream>>>(src, dst, efeat, offsets, rank, csr_sw);
    k_gather<<<(N_NODES * 64 + 255) / 256, 256, 0, stream>>>(offsets, csr_sw, featH, msum, aggH);
    fused_gemm<<<(N_NODES + 127) / 128, 512, 0, stream>>>(featH, aggH, WpH, bp, WsH, bs, msum, offsets, out);
}